// Round 1
// baseline (108.767 us; speedup 1.0000x reference)
//
#include <hip/hip_runtime.h>
#include <math.h>

// Base = R11 (86.5us, absmax 0.0). R12 change: phase-2 tap split widened
// from hf(2-way) to qf(4-way): thread = (oi, ojg, ocp, qf), 192 threads =
// 3 FULL waves (R11: 96 threads = 1 full + 1 half-masked wave). Per-thread
// fma halves (768->384); total LDS b128 count identical (3072 sc1 + 3072
// trig2 per image, same 3-window/oc-pair amortization). qf-reduction uses
// DPP quad_perm adds (VALU) instead of ds_bpermute shuffles (LDS pipe).
// Phase 1 / phase 3 / precompute bitwise identical to R11.
//
// d_ws trig layout (float2 = {cos,sin}):
//   [0,2880)    fft:   [n*288 + k]            (transposed ff_w trig)
//   [2880,3400) trig2: [ocp*130 + e*2 + (oc&1)], e = ch*16+ki*4+kj (pad 130)
//   [3400,3416) trig1: [oc*4 + e], e = a*2+c
#define FFT_OFF 0
#define W2_OFF 2880
#define W1_OFF 3400

__global__ void precompute_trig(const float* __restrict__ w1,
                                const float* __restrict__ w2,
                                const float* __restrict__ ff,
                                float2* __restrict__ ws) {
    int idx = blockIdx.x * blockDim.x + threadIdx.x;
    if (idx < 2880) {
        int k = idx / 10, n = idx % 10;
        float s, c; sincosf(ff[idx], &s, &c);
        ws[FFT_OFF + n * 288 + k] = make_float2(c, s);
    } else if (idx < 3392) {
        int i = idx - 2880;                  // i = oc*64 + e
        int oc = i >> 6, e = i & 63;
        float s, c; sincosf(w2[i], &s, &c);
        ws[W2_OFF + (oc >> 1) * 130 + e * 2 + (oc & 1)] = make_float2(c, s);
    } else if (idx < 3408) {
        int i = idx - 3392;
        float s, c; sincosf(w1[i], &s, &c);
        ws[W1_OFF + i] = make_float2(c, s);
    }
}

// DPP quad-butterfly sum over the 4 qf lanes (quads are fully active for
// tid < 192, so bound_ctrl is safe). Pure VALU: no LDS-pipe traffic.
__device__ __forceinline__ float quad_sum(float v) {
    v += __int_as_float(__builtin_amdgcn_mov_dpp(
             __float_as_int(v), 0xB1 /*quad_perm[1,0,3,2]*/, 0xF, 0xF, true));
    v += __int_as_float(__builtin_amdgcn_mov_dpp(
             __float_as_int(v), 0x4E /*quad_perm[2,3,0,1]*/, 0xF, 0xF, true));
    return v;
}

// 320 threads = 5 waves, 1 image/block, 4096 blocks.
// LDS: trig2 520f2 + sc1 1008f2 + sc2 288f2 = 14.5KB.
__global__ __launch_bounds__(320) void ringnn_kernel(
    const float* __restrict__ x,
    const float2* __restrict__ ws,
    float* __restrict__ out)
{
    __shared__ __align__(16) float2 trig2[520];
    __shared__ __align__(16) float2 sc1[1008];  // ch*252 + row*18 + col
    __shared__ __align__(16) float2 sc2[288];   // p*8 + oc
    const int tid = threadIdx.x;
    const float2* __restrict__ fft = ws + FFT_OFF;
    const float2* __restrict__ w1t = ws + W1_OFF;

    // ---- hoisted x loads (latency hides behind trig2 staging) ----
    int pi = (tid % 196) / 14, pj = tid % 14;
    float2 r0 = make_float2(0.f, 0.f), r1 = make_float2(0.f, 0.f);
    if (tid < 196) {
        const float* xb = x + (size_t)blockIdx.x * 784;
        r0 = *(const float2*)(xb + (2 * pi) * 28 + 2 * pj);
        r1 = *(const float2*)(xb + (2 * pi + 1) * 28 + 2 * pj);
    }

    // ---- stage trig2 from ws: pure b128 copies, no sincos ----
    if (tid < 260) ((float4*)trig2)[tid] = ((const float4*)(ws + W2_OFF))[tid];

    // ---- phase 1: ring conv1 (2x2 stride 2), thread = pos ----
    // trig1 read from global with wave-uniform address -> scalar load path;
    // P1 touches no LDS except the sc1 writes.
    if (tid < 196) {
        float sx[4], cx[4];
        __sincosf(r0.x, &sx[0], &cx[0]);
        __sincosf(r0.y, &sx[1], &cx[1]);
        __sincosf(r1.x, &sx[2], &cx[2]);
        __sincosf(r1.y, &sx[3], &cx[3]);
        #pragma unroll
        for (int oc = 0; oc < 4; oc++) {
            float4 wa = *(const float4*)(w1t + oc * 4);      // taps e0,e1 (uniform)
            float4 wb = *(const float4*)(w1t + oc * 4 + 2);  // taps e2,e3 (uniform)
            float Y = 0.f, X = 0.f;
            Y = fmaf(sx[0], wa.x, fmaf(-cx[0], wa.y, Y));
            X = fmaf(cx[0], wa.x, fmaf( sx[0], wa.y, X));
            Y = fmaf(sx[1], wa.z, fmaf(-cx[1], wa.w, Y));
            X = fmaf(cx[1], wa.z, fmaf( sx[1], wa.w, X));
            Y = fmaf(sx[2], wb.x, fmaf(-cx[2], wb.y, Y));
            X = fmaf(cx[2], wb.x, fmaf( sx[2], wb.y, X));
            Y = fmaf(sx[3], wb.z, fmaf(-cx[3], wb.w, Y));
            X = fmaf(cx[3], wb.z, fmaf( sx[3], wb.w, X));
            float inv = rsqrtf(fmaxf(fmaf(X, X, Y * Y), 1e-30f));
            sc1[oc * 252 + pi * 18 + pj] = make_float2(Y * inv, X * inv);
        }
    }
    __syncthreads();   // single barrier: covers trig2 staging AND sc1 writes

    // ---- phase 2: ring conv2 (4x4 stride 2) ----
    // thread = (oi, ojg, ocp, qf): 3 oj windows share an 8-col strip,
    // 2 oc share each weight read, qf = ki splits taps 4 ways.
    // 192 threads = 3 fully-active waves (no exec-masked half wave).
    if (tid < 192) {
        int r = tid;
        int qf = r & 3, ocp = (r >> 2) & 3, ojg = (r >> 4) & 1, oi = r >> 5;
        const int ki = qf;
        const float2* wbp = trig2 + ocp * 130;
        float aY[3][2] = {{0.f,0.f},{0.f,0.f},{0.f,0.f}};
        float aX[3][2] = {{0.f,0.f},{0.f,0.f},{0.f,0.f}};
        #pragma unroll
        for (int ch = 0; ch < 4; ch++) {
            int base = ch * 252 + (oi * 2 + ki) * 18 + ojg * 6;
            float4 f0 = *(const float4*)(sc1 + base);
            float4 f1 = *(const float4*)(sc1 + base + 2);
            float4 f2 = *(const float4*)(sc1 + base + 4);
            float4 f3 = *(const float4*)(sc1 + base + 6);
            float ss[8] = {f0.x,f0.z,f1.x,f1.z,f2.x,f2.z,f3.x,f3.z};
            float cc[8] = {f0.y,f0.w,f1.y,f1.w,f2.y,f2.w,f3.y,f3.w};
            int e0 = ch * 16 + ki * 4;
            #pragma unroll
            for (int kj = 0; kj < 4; kj++) {
                float4 wv = *(const float4*)(wbp + (e0 + kj) * 2); // (c0,s0,c1,s1)
                #pragma unroll
                for (int ojl = 0; ojl < 3; ojl++) {
                    float s = ss[ojl * 2 + kj], c = cc[ojl * 2 + kj];
                    aY[ojl][0] = fmaf(s, wv.x, fmaf(-c, wv.y, aY[ojl][0]));
                    aX[ojl][0] = fmaf(c, wv.x, fmaf( s, wv.y, aX[ojl][0]));
                    aY[ojl][1] = fmaf(s, wv.z, fmaf(-c, wv.w, aY[ojl][1]));
                    aX[ojl][1] = fmaf(c, wv.z, fmaf( s, wv.w, aX[ojl][1]));
                }
            }
        }
        #pragma unroll
        for (int ojl = 0; ojl < 3; ojl++) {
            float y0 = quad_sum(aY[ojl][0]);
            float y1 = quad_sum(aY[ojl][1]);
            float x0 = quad_sum(aX[ojl][0]);
            float x1 = quad_sum(aX[ojl][1]);
            float Y = (qf & 1) ? y1 : y0;
            float X = (qf & 1) ? x1 : x0;
            float inv = rsqrtf(fmaxf(fmaf(X, X, Y * Y), 1e-30f));
            int p = oi * 6 + ojg * 3 + ojl;
            if (qf < 2) sc2[p * 8 + ocp * 2 + qf] = make_float2(Y * inv, X * inv);
        }
    }
    __syncthreads();

    // ---- phase 3: ring feed-forward; thread = (n, s32) ----
    {
        int n = tid >> 5, s = tid & 31;
        const float2* wn = fft + n * 288;
        float Y = 0.f, X = 0.f;
        #pragma unroll
        for (int i = 0; i < 9; i++) {
            int k = i * 32 + s;
            float2 sc = sc2[k];
            float2 w = wn[k];
            Y = fmaf(sc.x, w.x, fmaf(-sc.y, w.y, Y));
            X = fmaf(sc.y, w.x, fmaf( sc.x, w.y, X));
        }
        #pragma unroll
        for (int off = 16; off > 0; off >>= 1) {
            Y += __shfl_down(Y, off, 32);
            X += __shfl_down(X, off, 32);
        }
        if (s == 0) {
            out[(size_t)blockIdx.x * 10 + n] =
                Y * rsqrtf(fmaxf(fmaf(X, X, Y * Y), 1e-30f));
        }
    }
}

extern "C" void kernel_launch(void* const* d_in, const int* in_sizes, int n_in,
                              void* d_out, int out_size, void* d_ws, size_t ws_size,
                              hipStream_t stream) {
    const float* x  = (const float*)d_in[0];
    const float* w1 = (const float*)d_in[1];
    const float* w2 = (const float*)d_in[2];
    const float* ff = (const float*)d_in[3];
    float* out = (float*)d_out;
    const int B = in_sizes[0] / 784;   // 4096

    float2* ws = (float2*)d_ws;
    precompute_trig<<<14, 256, 0, stream>>>(w1, w2, ff, ws);
    ringnn_kernel<<<B, 320, 0, stream>>>(x, ws, out);
}

// Round 2
// 85.009 us; speedup vs baseline: 1.2795x; 1.2795x over previous
//
#include <hip/hip_runtime.h>
#include <math.h>

// Base = R11 arithmetic (known-good 86.5us, absmax 0.0). R13 change: block
// shrunk 320->128 threads (2 waves), still 1 image/block. Same LDS (14.5KB),
// VGPR band unchanged -> 8 resident blocks/CU (was 3): 2.7x more independent
// blocks to hide barrier/LDS latency; barriers are 2-wave rendezvous.
//   - phase 1: 196 positions in 2 rounds/thread (round 1: tid<68), math
//     per-position bitwise identical to R11.
//   - phase 2: R11's 96-thread (oi,ojg,ocp,hf) code VERBATIM (wave0 full +
//     wave1 half-masked = 75% of block lanes; was 30% of a 5-wave block).
//     Reverts R12's qf-split (it inflated per-image LDS-pipe instrs 1.5x).
//   - phase 3: R11's (n, s32) mapping run in 3 rounds of 128 (round 2:
//     wave 0 only), per-output math bitwise identical.
//
// d_ws trig layout (float2 = {cos,sin}):
//   [0,2880)    fft:   [n*288 + k]            (transposed ff_w trig)
//   [2880,3400) trig2: [ocp*130 + e*2 + (oc&1)], e = ch*16+ki*4+kj (pad 130)
//   [3400,3416) trig1: [oc*4 + e], e = a*2+c
#define FFT_OFF 0
#define W2_OFF 2880
#define W1_OFF 3400

__global__ void precompute_trig(const float* __restrict__ w1,
                                const float* __restrict__ w2,
                                const float* __restrict__ ff,
                                float2* __restrict__ ws) {
    int idx = blockIdx.x * blockDim.x + threadIdx.x;
    if (idx < 2880) {
        int k = idx / 10, n = idx % 10;
        float s, c; sincosf(ff[idx], &s, &c);
        ws[FFT_OFF + n * 288 + k] = make_float2(c, s);
    } else if (idx < 3392) {
        int i = idx - 2880;                  // i = oc*64 + e
        int oc = i >> 6, e = i & 63;
        float s, c; sincosf(w2[i], &s, &c);
        ws[W2_OFF + (oc >> 1) * 130 + e * 2 + (oc & 1)] = make_float2(c, s);
    } else if (idx < 3408) {
        int i = idx - 3392;
        float s, c; sincosf(w1[i], &s, &c);
        ws[W1_OFF + i] = make_float2(c, s);
    }
}

// One conv1 output position: 4 sincos + 4 oc x (16 fma + rsqrt).
// Bitwise identical to R11's per-position phase-1 body.
__device__ __forceinline__ void conv1_pos(float2 r0, float2 r1,
                                          const float2* __restrict__ w1t,
                                          float2* __restrict__ sc1,
                                          int pi, int pj) {
    float sx[4], cx[4];
    __sincosf(r0.x, &sx[0], &cx[0]);
    __sincosf(r0.y, &sx[1], &cx[1]);
    __sincosf(r1.x, &sx[2], &cx[2]);
    __sincosf(r1.y, &sx[3], &cx[3]);
    #pragma unroll
    for (int oc = 0; oc < 4; oc++) {
        float4 wa = *(const float4*)(w1t + oc * 4);      // taps e0,e1 (uniform)
        float4 wb = *(const float4*)(w1t + oc * 4 + 2);  // taps e2,e3 (uniform)
        float Y = 0.f, X = 0.f;
        Y = fmaf(sx[0], wa.x, fmaf(-cx[0], wa.y, Y));
        X = fmaf(cx[0], wa.x, fmaf( sx[0], wa.y, X));
        Y = fmaf(sx[1], wa.z, fmaf(-cx[1], wa.w, Y));
        X = fmaf(cx[1], wa.z, fmaf( sx[1], wa.w, X));
        Y = fmaf(sx[2], wb.x, fmaf(-cx[2], wb.y, Y));
        X = fmaf(cx[2], wb.x, fmaf( sx[2], wb.y, X));
        Y = fmaf(sx[3], wb.z, fmaf(-cx[3], wb.w, Y));
        X = fmaf(cx[3], wb.z, fmaf( sx[3], wb.w, X));
        float inv = rsqrtf(fmaxf(fmaf(X, X, Y * Y), 1e-30f));
        sc1[oc * 252 + pi * 18 + pj] = make_float2(Y * inv, X * inv);
    }
}

// 128 threads = 2 waves, 1 image/block, 4096 blocks. 8 blocks/CU resident.
// LDS: trig2 520f2 + sc1 1008f2 + sc2 288f2 = 14.5KB.
__global__ __launch_bounds__(128, 4) void ringnn_kernel(
    const float* __restrict__ x,
    const float2* __restrict__ ws,
    float* __restrict__ out)
{
    __shared__ __align__(16) float2 trig2[520];
    __shared__ __align__(16) float2 sc1[1008];  // ch*252 + row*18 + col
    __shared__ __align__(16) float2 sc2[288];   // p*8 + oc
    const int tid = threadIdx.x;
    const float2* __restrict__ fft = ws + FFT_OFF;
    const float2* __restrict__ w1t = ws + W1_OFF;

    // ---- hoisted x loads for both phase-1 rounds ----
    const float* xb = x + (size_t)blockIdx.x * 784;
    const int pi0 = tid / 14, pj0 = tid % 14;            // round 0: pos = tid (<196 always)
    float2 a0 = *(const float2*)(xb + (2 * pi0) * 28 + 2 * pj0);
    float2 a1 = *(const float2*)(xb + (2 * pi0 + 1) * 28 + 2 * pj0);
    const int p1 = tid + 128;                            // round 1: tid < 68
    int pi1 = 0, pj1 = 0;
    float2 b0 = make_float2(0.f, 0.f), b1 = make_float2(0.f, 0.f);
    if (p1 < 196) {
        pi1 = p1 / 14; pj1 = p1 % 14;
        b0 = *(const float2*)(xb + (2 * pi1) * 28 + 2 * pj1);
        b1 = *(const float2*)(xb + (2 * pi1 + 1) * 28 + 2 * pj1);
    }

    // ---- stage trig2 from ws: pure b128 copies, no sincos (3 rounds) ----
    for (int i = tid; i < 260; i += 128)
        ((float4*)trig2)[i] = ((const float4*)(ws + W2_OFF))[i];

    // ---- phase 1: ring conv1 (2x2 stride 2), 196 positions in 2 rounds ----
    conv1_pos(a0, a1, w1t, sc1, pi0, pj0);
    if (p1 < 196) conv1_pos(b0, b1, w1t, sc1, pi1, pj1);
    __syncthreads();   // single barrier: covers trig2 staging AND sc1 writes

    // ---- phase 2: ring conv2 (4x4 stride 2) -- R11 verbatim ----
    // thread = (oi, ojg, ocp, hf): 3 oj windows share an 8-col strip,
    // 2 oc share each weight read, hf splits taps by ki{0,1}|{2,3}.
    if (tid < 96) {
        int r = tid;
        int oi = r >> 4, ojg = (r >> 3) & 1, ocp = (r >> 1) & 3, hf = r & 1;
        const float2* wbp = trig2 + ocp * 130;
        float aY[3][2] = {{0.f,0.f},{0.f,0.f},{0.f,0.f}};
        float aX[3][2] = {{0.f,0.f},{0.f,0.f},{0.f,0.f}};
        #pragma unroll
        for (int ch = 0; ch < 4; ch++) {
            #pragma unroll
            for (int kk = 0; kk < 2; kk++) {
                int ki = hf * 2 + kk;
                int base = ch * 252 + (oi * 2 + ki) * 18 + ojg * 6;
                float4 f0 = *(const float4*)(sc1 + base);
                float4 f1 = *(const float4*)(sc1 + base + 2);
                float4 f2 = *(const float4*)(sc1 + base + 4);
                float4 f3 = *(const float4*)(sc1 + base + 6);
                float ss[8] = {f0.x,f0.z,f1.x,f1.z,f2.x,f2.z,f3.x,f3.z};
                float cc[8] = {f0.y,f0.w,f1.y,f1.w,f2.y,f2.w,f3.y,f3.w};
                int e0 = ch * 16 + ki * 4;
                #pragma unroll
                for (int kj = 0; kj < 4; kj++) {
                    float4 wv = *(const float4*)(wbp + (e0 + kj) * 2); // (c0,s0,c1,s1)
                    #pragma unroll
                    for (int ojl = 0; ojl < 3; ojl++) {
                        float s = ss[ojl * 2 + kj], c = cc[ojl * 2 + kj];
                        aY[ojl][0] = fmaf(s, wv.x, fmaf(-c, wv.y, aY[ojl][0]));
                        aX[ojl][0] = fmaf(c, wv.x, fmaf( s, wv.y, aX[ojl][0]));
                        aY[ojl][1] = fmaf(s, wv.z, fmaf(-c, wv.w, aY[ojl][1]));
                        aX[ojl][1] = fmaf(c, wv.z, fmaf( s, wv.w, aX[ojl][1]));
                    }
                }
            }
        }
        #pragma unroll
        for (int ojl = 0; ojl < 3; ojl++) {
            float y0 = aY[ojl][0]; y0 += __shfl_xor(y0, 1);
            float y1 = aY[ojl][1]; y1 += __shfl_xor(y1, 1);
            float x0 = aX[ojl][0]; x0 += __shfl_xor(x0, 1);
            float x1 = aX[ojl][1]; x1 += __shfl_xor(x1, 1);
            float Y = hf ? y1 : y0;
            float X = hf ? x1 : x0;
            float inv = rsqrtf(fmaxf(fmaf(X, X, Y * Y), 1e-30f));
            int p = oi * 6 + ojg * 3 + ojl;
            sc2[p * 8 + ocp * 2 + hf] = make_float2(Y * inv, X * inv);
        }
    }
    __syncthreads();

    // ---- phase 3: ring feed-forward; (n, s32) mapping in 3 rounds ----
    #pragma unroll
    for (int rr = 0; rr < 3; rr++) {
        int idx = tid + (rr << 7);
        if (idx < 320) {                 // round 2: wave 0 only (uniform skip on wave 1)
            int n = idx >> 5, s = idx & 31;
            const float2* wn = fft + n * 288;
            float Y = 0.f, X = 0.f;
            #pragma unroll
            for (int i = 0; i < 9; i++) {
                int k = i * 32 + s;
                float2 sc = sc2[k];
                float2 w = wn[k];
                Y = fmaf(sc.x, w.x, fmaf(-sc.y, w.y, Y));
                X = fmaf(sc.y, w.x, fmaf( sc.x, w.y, X));
            }
            #pragma unroll
            for (int off = 16; off > 0; off >>= 1) {
                Y += __shfl_down(Y, off, 32);
                X += __shfl_down(X, off, 32);
            }
            if (s == 0) {
                out[(size_t)blockIdx.x * 10 + n] =
                    Y * rsqrtf(fmaxf(fmaf(X, X, Y * Y), 1e-30f));
            }
        }
    }
}

extern "C" void kernel_launch(void* const* d_in, const int* in_sizes, int n_in,
                              void* d_out, int out_size, void* d_ws, size_t ws_size,
                              hipStream_t stream) {
    const float* x  = (const float*)d_in[0];
    const float* w1 = (const float*)d_in[1];
    const float* w2 = (const float*)d_in[2];
    const float* ff = (const float*)d_in[3];
    float* out = (float*)d_out;
    const int B = in_sizes[0] / 784;   // 4096

    float2* ws = (float2*)d_ws;
    precompute_trig<<<14, 256, 0, stream>>>(w1, w2, ff, ws);
    ringnn_kernel<<<B, 128, 0, stream>>>(x, ws, out);
}

// Round 3
// 82.385 us; speedup vs baseline: 1.3202x; 1.0318x over previous
//
#include <hip/hip_runtime.h>
#include <math.h>

// Base = R13 (85.0us, absmax 0.0; per-task math bitwise = R11). R14 change:
// 2 images per block, 256 threads (4 waves), grid 2048. Per-image overhead
// (trig2 staging, barriers, launch) halved; lane utilization up in every
// phase (P2: 192/256 = 3 FULL waves, was 96/128); 2 images' independent
// dep-chains hide each other's latency. Per-position/per-output arithmetic
// is bitwise identical to R11/R13 -- only thread->task maps change.
//   LDS: trig2 520 + 2*sc1 1008 + 2*sc2 288 = 3112 f2 = 24.9KB.
//
// d_ws trig layout (float2 = {cos,sin}):
//   [0,2880)    fft:   [n*288 + k]            (transposed ff_w trig)
//   [2880,3400) trig2: [ocp*130 + e*2 + (oc&1)], e = ch*16+ki*4+kj (pad 130)
//   [3400,3416) trig1: [oc*4 + e], e = a*2+c
#define FFT_OFF 0
#define W2_OFF 2880
#define W1_OFF 3400

__global__ void precompute_trig(const float* __restrict__ w1,
                                const float* __restrict__ w2,
                                const float* __restrict__ ff,
                                float2* __restrict__ ws) {
    int idx = blockIdx.x * blockDim.x + threadIdx.x;
    if (idx < 2880) {
        int k = idx / 10, n = idx % 10;
        float s, c; sincosf(ff[idx], &s, &c);
        ws[FFT_OFF + n * 288 + k] = make_float2(c, s);
    } else if (idx < 3392) {
        int i = idx - 2880;                  // i = oc*64 + e
        int oc = i >> 6, e = i & 63;
        float s, c; sincosf(w2[i], &s, &c);
        ws[W2_OFF + (oc >> 1) * 130 + e * 2 + (oc & 1)] = make_float2(c, s);
    } else if (idx < 3408) {
        int i = idx - 3392;
        float s, c; sincosf(w1[i], &s, &c);
        ws[W1_OFF + i] = make_float2(c, s);
    }
}

// One conv1 output position: 4 sincos + 4 oc x (16 fma + rsqrt).
// Bitwise identical to R11's per-position phase-1 body.
__device__ __forceinline__ void conv1_pos(float2 r0, float2 r1,
                                          const float2* __restrict__ w1t,
                                          float2* __restrict__ sc1,
                                          int pi, int pj) {
    float sx[4], cx[4];
    __sincosf(r0.x, &sx[0], &cx[0]);
    __sincosf(r0.y, &sx[1], &cx[1]);
    __sincosf(r1.x, &sx[2], &cx[2]);
    __sincosf(r1.y, &sx[3], &cx[3]);
    #pragma unroll
    for (int oc = 0; oc < 4; oc++) {
        float4 wa = *(const float4*)(w1t + oc * 4);      // taps e0,e1 (uniform)
        float4 wb = *(const float4*)(w1t + oc * 4 + 2);  // taps e2,e3 (uniform)
        float Y = 0.f, X = 0.f;
        Y = fmaf(sx[0], wa.x, fmaf(-cx[0], wa.y, Y));
        X = fmaf(cx[0], wa.x, fmaf( sx[0], wa.y, X));
        Y = fmaf(sx[1], wa.z, fmaf(-cx[1], wa.w, Y));
        X = fmaf(cx[1], wa.z, fmaf( sx[1], wa.w, X));
        Y = fmaf(sx[2], wb.x, fmaf(-cx[2], wb.y, Y));
        X = fmaf(cx[2], wb.x, fmaf( sx[2], wb.y, X));
        Y = fmaf(sx[3], wb.z, fmaf(-cx[3], wb.w, Y));
        X = fmaf(cx[3], wb.z, fmaf( sx[3], wb.w, X));
        float inv = rsqrtf(fmaxf(fmaf(X, X, Y * Y), 1e-30f));
        sc1[oc * 252 + pi * 18 + pj] = make_float2(Y * inv, X * inv);
    }
}

// 256 threads = 4 waves, 2 images/block, 2048 blocks.
__global__ __launch_bounds__(256, 4) void ringnn_kernel(
    const float* __restrict__ x,
    const float2* __restrict__ ws,
    float* __restrict__ out)
{
    __shared__ __align__(16) float2 trig2[520];
    __shared__ __align__(16) float2 sc1[2 * 1008]; // img*1008 + ch*252 + row*18 + col
    __shared__ __align__(16) float2 sc2[2 * 288];  // img*288 + p*8 + oc
    const int tid = threadIdx.x;
    const float2* __restrict__ fft = ws + FFT_OFF;
    const float2* __restrict__ w1t = ws + W1_OFF;
    const size_t img0 = (size_t)blockIdx.x * 2;

    // ---- hoisted x loads for both phase-1 rounds (2 images) ----
    // round 0: task = tid in [0,256): img = tid>=196, pos = tid - img*196
    // round 1: task = tid+256 in [256,392): img 1, pos = tid+60 (tid<136)
    const int im0 = (tid >= 196) ? 1 : 0;
    const int p0  = tid - im0 * 196;
    const int pi0 = p0 / 14, pj0 = p0 % 14;
    const float* xb0 = x + (img0 + im0) * 784;
    float2 a0 = *(const float2*)(xb0 + (2 * pi0) * 28 + 2 * pj0);
    float2 a1 = *(const float2*)(xb0 + (2 * pi0 + 1) * 28 + 2 * pj0);
    int pi1 = 0, pj1 = 0;
    float2 b0 = make_float2(0.f, 0.f), b1 = make_float2(0.f, 0.f);
    if (tid < 136) {
        int p = tid + 60;                    // img 1, pos 60..195
        pi1 = p / 14; pj1 = p % 14;
        const float* xb1 = x + (img0 + 1) * 784;
        b0 = *(const float2*)(xb1 + (2 * pi1) * 28 + 2 * pj1);
        b1 = *(const float2*)(xb1 + (2 * pi1 + 1) * 28 + 2 * pj1);
    }

    // ---- stage trig2 from ws: pure b128 copies, once per 2 images ----
    for (int i = tid; i < 260; i += 256)
        ((float4*)trig2)[i] = ((const float4*)(ws + W2_OFF))[i];

    // ---- phase 1: ring conv1 (2x2 stride 2), 392 tasks in 2 rounds ----
    conv1_pos(a0, a1, w1t, sc1 + im0 * 1008, pi0, pj0);
    if (tid < 136) conv1_pos(b0, b1, w1t, sc1 + 1008, pi1, pj1);
    __syncthreads();   // single barrier: covers trig2 staging AND sc1 writes

    // ---- phase 2: ring conv2 (4x4 stride 2); 192 tasks = 3 full waves ----
    // task = (img, oi, ojg, ocp, hf): per-task code identical to R11.
    if (tid < 192) {
        const int img = (tid >= 96) ? 1 : 0;
        int r = tid - img * 96;
        int oi = r >> 4, ojg = (r >> 3) & 1, ocp = (r >> 1) & 3, hf = r & 1;
        const float2* wbp = trig2 + ocp * 130;
        const float2* s1p = sc1 + img * 1008;
        float aY[3][2] = {{0.f,0.f},{0.f,0.f},{0.f,0.f}};
        float aX[3][2] = {{0.f,0.f},{0.f,0.f},{0.f,0.f}};
        #pragma unroll
        for (int ch = 0; ch < 4; ch++) {
            #pragma unroll
            for (int kk = 0; kk < 2; kk++) {
                int ki = hf * 2 + kk;
                int base = ch * 252 + (oi * 2 + ki) * 18 + ojg * 6;
                float4 f0 = *(const float4*)(s1p + base);
                float4 f1 = *(const float4*)(s1p + base + 2);
                float4 f2 = *(const float4*)(s1p + base + 4);
                float4 f3 = *(const float4*)(s1p + base + 6);
                float ss[8] = {f0.x,f0.z,f1.x,f1.z,f2.x,f2.z,f3.x,f3.z};
                float cc[8] = {f0.y,f0.w,f1.y,f1.w,f2.y,f2.w,f3.y,f3.w};
                int e0 = ch * 16 + ki * 4;
                #pragma unroll
                for (int kj = 0; kj < 4; kj++) {
                    float4 wv = *(const float4*)(wbp + (e0 + kj) * 2); // (c0,s0,c1,s1)
                    #pragma unroll
                    for (int ojl = 0; ojl < 3; ojl++) {
                        float s = ss[ojl * 2 + kj], c = cc[ojl * 2 + kj];
                        aY[ojl][0] = fmaf(s, wv.x, fmaf(-c, wv.y, aY[ojl][0]));
                        aX[ojl][0] = fmaf(c, wv.x, fmaf( s, wv.y, aX[ojl][0]));
                        aY[ojl][1] = fmaf(s, wv.z, fmaf(-c, wv.w, aY[ojl][1]));
                        aX[ojl][1] = fmaf(c, wv.z, fmaf( s, wv.w, aX[ojl][1]));
                    }
                }
            }
        }
        // pairs (even,odd) lanes: img*96 offset is even, so pairs never
        // straddle images; __shfl_xor(,1) semantics identical to R11.
        #pragma unroll
        for (int ojl = 0; ojl < 3; ojl++) {
            float y0 = aY[ojl][0]; y0 += __shfl_xor(y0, 1);
            float y1 = aY[ojl][1]; y1 += __shfl_xor(y1, 1);
            float x0 = aX[ojl][0]; x0 += __shfl_xor(x0, 1);
            float x1 = aX[ojl][1]; x1 += __shfl_xor(x1, 1);
            float Y = hf ? y1 : y0;
            float X = hf ? x1 : x0;
            float inv = rsqrtf(fmaxf(fmaf(X, X, Y * Y), 1e-30f));
            int p = oi * 6 + ojg * 3 + ojl;
            sc2[img * 288 + p * 8 + ocp * 2 + hf] = make_float2(Y * inv, X * inv);
        }
    }
    __syncthreads();

    // ---- phase 3: ring feed-forward; 640 tasks = (img, n, s32), 3 rounds ----
    #pragma unroll
    for (int rr = 0; rr < 3; rr++) {
        int t = tid + (rr << 8);
        if (t < 640) {                 // round 2: tid<128 (wave 0-1 only)
            int img = (t >= 320) ? 1 : 0;
            int idx = t - img * 320;
            int n = idx >> 5, s = idx & 31;
            const float2* wn = fft + n * 288;
            const float2* s2p = sc2 + img * 288;
            float Y = 0.f, X = 0.f;
            #pragma unroll
            for (int i = 0; i < 9; i++) {
                int k = i * 32 + s;
                float2 sc = s2p[k];
                float2 w = wn[k];
                Y = fmaf(sc.x, w.x, fmaf(-sc.y, w.y, Y));
                X = fmaf(sc.y, w.x, fmaf( sc.x, w.y, X));
            }
            #pragma unroll
            for (int off = 16; off > 0; off >>= 1) {
                Y += __shfl_down(Y, off, 32);
                X += __shfl_down(X, off, 32);
            }
            if (s == 0) {
                out[(img0 + img) * 10 + n] =
                    Y * rsqrtf(fmaxf(fmaf(X, X, Y * Y), 1e-30f));
            }
        }
    }
}

extern "C" void kernel_launch(void* const* d_in, const int* in_sizes, int n_in,
                              void* d_out, int out_size, void* d_ws, size_t ws_size,
                              hipStream_t stream) {
    const float* x  = (const float*)d_in[0];
    const float* w1 = (const float*)d_in[1];
    const float* w2 = (const float*)d_in[2];
    const float* ff = (const float*)d_in[3];
    float* out = (float*)d_out;
    const int B = in_sizes[0] / 784;   // 4096

    float2* ws = (float2*)d_ws;
    precompute_trig<<<14, 256, 0, stream>>>(w1, w2, ff, ws);
    ringnn_kernel<<<B / 2, 256, 0, stream>>>(x, ws, out);
}

// Round 4
// 82.103 us; speedup vs baseline: 1.3248x; 1.0034x over previous
//
#include <hip/hip_runtime.h>
#include <math.h>

// Base = R14 (82.4us; per-task math bitwise = R11). R15 change: persistent
// co-resident blocks. Grid = B/4 = 1024 blocks = EXACTLY 4 blocks/CU, each
// processing 4 images (two R14 pairs). All blocks resident simultaneously
// (LDS 24.9KB -> 6/CU cap, launch_bounds(256,4) -> 16 waves/CU): the grid
// dispatches once, zero workgroup churn, zero tail. Pair loop is software-
// pipelined: pair1's x-loads + phase1 (VALU/sincos) run in the same barrier
// interval as pair0's phase3 (LDS/L2 reads) -- disjoint buffers (phase3
// reads sc2; phase1 writes sc1 whose last readers finished at the post-P2
// barrier). trig2 staged once per 4 images. Arithmetic bitwise = R11/R14.
//
// d_ws trig layout (float2 = {cos,sin}):
//   [0,2880)    fft:   [n*288 + k]            (transposed ff_w trig)
//   [2880,3400) trig2: [ocp*130 + e*2 + (oc&1)], e = ch*16+ki*4+kj (pad 130)
//   [3400,3416) trig1: [oc*4 + e], e = a*2+c
#define FFT_OFF 0
#define W2_OFF 2880
#define W1_OFF 3400

__global__ void precompute_trig(const float* __restrict__ w1,
                                const float* __restrict__ w2,
                                const float* __restrict__ ff,
                                float2* __restrict__ ws) {
    int idx = blockIdx.x * blockDim.x + threadIdx.x;
    if (idx < 2880) {
        int k = idx / 10, n = idx % 10;
        float s, c; sincosf(ff[idx], &s, &c);
        ws[FFT_OFF + n * 288 + k] = make_float2(c, s);
    } else if (idx < 3392) {
        int i = idx - 2880;                  // i = oc*64 + e
        int oc = i >> 6, e = i & 63;
        float s, c; sincosf(w2[i], &s, &c);
        ws[W2_OFF + (oc >> 1) * 130 + e * 2 + (oc & 1)] = make_float2(c, s);
    } else if (idx < 3408) {
        int i = idx - 3392;
        float s, c; sincosf(w1[i], &s, &c);
        ws[W1_OFF + i] = make_float2(c, s);
    }
}

// One conv1 output position: 4 sincos + 4 oc x (16 fma + rsqrt).
// Bitwise identical to R11's per-position phase-1 body.
__device__ __forceinline__ void conv1_pos(float2 r0, float2 r1,
                                          const float2* __restrict__ w1t,
                                          float2* __restrict__ sc1,
                                          int pi, int pj) {
    float sx[4], cx[4];
    __sincosf(r0.x, &sx[0], &cx[0]);
    __sincosf(r0.y, &sx[1], &cx[1]);
    __sincosf(r1.x, &sx[2], &cx[2]);
    __sincosf(r1.y, &sx[3], &cx[3]);
    #pragma unroll
    for (int oc = 0; oc < 4; oc++) {
        float4 wa = *(const float4*)(w1t + oc * 4);      // taps e0,e1 (uniform)
        float4 wb = *(const float4*)(w1t + oc * 4 + 2);  // taps e2,e3 (uniform)
        float Y = 0.f, X = 0.f;
        Y = fmaf(sx[0], wa.x, fmaf(-cx[0], wa.y, Y));
        X = fmaf(cx[0], wa.x, fmaf( sx[0], wa.y, X));
        Y = fmaf(sx[1], wa.z, fmaf(-cx[1], wa.w, Y));
        X = fmaf(cx[1], wa.z, fmaf( sx[1], wa.w, X));
        Y = fmaf(sx[2], wb.x, fmaf(-cx[2], wb.y, Y));
        X = fmaf(cx[2], wb.x, fmaf( sx[2], wb.y, X));
        Y = fmaf(sx[3], wb.z, fmaf(-cx[3], wb.w, Y));
        X = fmaf(cx[3], wb.z, fmaf( sx[3], wb.w, X));
        float inv = rsqrtf(fmaxf(fmaf(X, X, Y * Y), 1e-30f));
        sc1[oc * 252 + pi * 18 + pj] = make_float2(Y * inv, X * inv);
    }
}

// 256 threads = 4 waves, 4 images/block (2 pairs), grid B/4 = 1024.
__global__ __launch_bounds__(256, 4) void ringnn_kernel(
    const float* __restrict__ x,
    const float2* __restrict__ ws,
    float* __restrict__ out)
{
    __shared__ __align__(16) float2 trig2[520];
    __shared__ __align__(16) float2 sc1[2 * 1008]; // img*1008 + ch*252 + row*18 + col
    __shared__ __align__(16) float2 sc2[2 * 288];  // img*288 + p*8 + oc
    const int tid = threadIdx.x;
    const float2* __restrict__ fft = ws + FFT_OFF;
    const float2* __restrict__ w1t = ws + W1_OFF;
    const size_t imgBase = (size_t)blockIdx.x * 4;

    // ---- per-thread position maps (constant across pairs) ----
    const int im0 = (tid >= 196) ? 1 : 0;
    const int p0  = tid - im0 * 196;
    const int pi0 = p0 / 14, pj0 = p0 % 14;
    const int pr1 = tid + 60;                   // img1 pos for round 1 (tid<136)
    const int pi1 = pr1 / 14, pj1 = pr1 % 14;

    float2 a0, a1, b0 = make_float2(0.f, 0.f), b1 = make_float2(0.f, 0.f);

    auto loadPair = [&](size_t pairImg) {
        const float* xb0 = x + (pairImg + im0) * 784;
        a0 = *(const float2*)(xb0 + (2 * pi0) * 28 + 2 * pj0);
        a1 = *(const float2*)(xb0 + (2 * pi0 + 1) * 28 + 2 * pj0);
        if (tid < 136) {
            const float* xb1 = x + (pairImg + 1) * 784;
            b0 = *(const float2*)(xb1 + (2 * pi1) * 28 + 2 * pj1);
            b1 = *(const float2*)(xb1 + (2 * pi1 + 1) * 28 + 2 * pj1);
        }
    };

    // phase 1: 392 tasks in 2 rounds; per-position math bitwise = R11.
    auto phase1 = [&]() {
        conv1_pos(a0, a1, w1t, sc1 + im0 * 1008, pi0, pj0);
        if (tid < 136) conv1_pos(b0, b1, w1t, sc1 + 1008, pi1, pj1);
    };

    // phase 2: 192 tasks = (img, oi, ojg, ocp, hf); per-task code = R11.
    auto phase2 = [&]() {
        if (tid < 192) {
            const int img = (tid >= 96) ? 1 : 0;
            int r = tid - img * 96;
            int oi = r >> 4, ojg = (r >> 3) & 1, ocp = (r >> 1) & 3, hf = r & 1;
            const float2* wbp = trig2 + ocp * 130;
            const float2* s1p = sc1 + img * 1008;
            float aY[3][2] = {{0.f,0.f},{0.f,0.f},{0.f,0.f}};
            float aX[3][2] = {{0.f,0.f},{0.f,0.f},{0.f,0.f}};
            #pragma unroll
            for (int ch = 0; ch < 4; ch++) {
                #pragma unroll
                for (int kk = 0; kk < 2; kk++) {
                    int ki = hf * 2 + kk;
                    int base = ch * 252 + (oi * 2 + ki) * 18 + ojg * 6;
                    float4 f0 = *(const float4*)(s1p + base);
                    float4 f1 = *(const float4*)(s1p + base + 2);
                    float4 f2 = *(const float4*)(s1p + base + 4);
                    float4 f3 = *(const float4*)(s1p + base + 6);
                    float ss[8] = {f0.x,f0.z,f1.x,f1.z,f2.x,f2.z,f3.x,f3.z};
                    float cc[8] = {f0.y,f0.w,f1.y,f1.w,f2.y,f2.w,f3.y,f3.w};
                    int e0 = ch * 16 + ki * 4;
                    #pragma unroll
                    for (int kj = 0; kj < 4; kj++) {
                        float4 wv = *(const float4*)(wbp + (e0 + kj) * 2); // (c0,s0,c1,s1)
                        #pragma unroll
                        for (int ojl = 0; ojl < 3; ojl++) {
                            float s = ss[ojl * 2 + kj], c = cc[ojl * 2 + kj];
                            aY[ojl][0] = fmaf(s, wv.x, fmaf(-c, wv.y, aY[ojl][0]));
                            aX[ojl][0] = fmaf(c, wv.x, fmaf( s, wv.y, aX[ojl][0]));
                            aY[ojl][1] = fmaf(s, wv.z, fmaf(-c, wv.w, aY[ojl][1]));
                            aX[ojl][1] = fmaf(c, wv.z, fmaf( s, wv.w, aX[ojl][1]));
                        }
                    }
                }
            }
            // even/odd lane pairs; img offset 96 is even -> pairs never
            // straddle images; __shfl_xor(,1) semantics identical to R11.
            #pragma unroll
            for (int ojl = 0; ojl < 3; ojl++) {
                float y0 = aY[ojl][0]; y0 += __shfl_xor(y0, 1);
                float y1 = aY[ojl][1]; y1 += __shfl_xor(y1, 1);
                float x0 = aX[ojl][0]; x0 += __shfl_xor(x0, 1);
                float x1 = aX[ojl][1]; x1 += __shfl_xor(x1, 1);
                float Y = hf ? y1 : y0;
                float X = hf ? x1 : x0;
                float inv = rsqrtf(fmaxf(fmaf(X, X, Y * Y), 1e-30f));
                int p = oi * 6 + ojg * 3 + ojl;
                sc2[img * 288 + p * 8 + ocp * 2 + hf] = make_float2(Y * inv, X * inv);
            }
        }
    };

    // phase 3: 640 tasks = (img, n, s32) in 3 rounds; per-output math = R11.
    auto phase3 = [&](size_t pairImg) {
        #pragma unroll
        for (int rr = 0; rr < 3; rr++) {
            int t = tid + (rr << 8);
            if (t < 640) {
                int img = (t >= 320) ? 1 : 0;
                int idx = t - img * 320;
                int n = idx >> 5, s = idx & 31;
                const float2* wn = fft + n * 288;
                const float2* s2p = sc2 + img * 288;
                float Y = 0.f, X = 0.f;
                #pragma unroll
                for (int i = 0; i < 9; i++) {
                    int k = i * 32 + s;
                    float2 sc = s2p[k];
                    float2 w = wn[k];
                    Y = fmaf(sc.x, w.x, fmaf(-sc.y, w.y, Y));
                    X = fmaf(sc.y, w.x, fmaf( sc.x, w.y, X));
                }
                #pragma unroll
                for (int off = 16; off > 0; off >>= 1) {
                    Y += __shfl_down(Y, off, 32);
                    X += __shfl_down(X, off, 32);
                }
                if (s == 0) {
                    out[(pairImg + img) * 10 + n] =
                        Y * rsqrtf(fmaxf(fmaf(X, X, Y * Y), 1e-30f));
                }
            }
        }
    };

    // ---- persistent 4-image schedule (2 pairs, software-pipelined) ----
    loadPair(imgBase);
    for (int i = tid; i < 260; i += 256)                 // trig2: once per block
        ((float4*)trig2)[i] = ((const float4*)(ws + W2_OFF))[i];
    phase1();
    __syncthreads();          // trig2 staged + pair0 sc1 ready
    phase2();
    __syncthreads();          // pair0 sc2 ready; sc1 free
    loadPair(imgBase + 2);    // pair1 x-loads: latency hides under phase3
    phase3(imgBase);          // reads sc2 (pair0)
    phase1();                 // writes sc1 (pair1) -- disjoint from phase3
    __syncthreads();          // pair1 sc1 ready; sc2 free
    phase2();
    __syncthreads();          // pair1 sc2 ready
    phase3(imgBase + 2);
}

extern "C" void kernel_launch(void* const* d_in, const int* in_sizes, int n_in,
                              void* d_out, int out_size, void* d_ws, size_t ws_size,
                              hipStream_t stream) {
    const float* x  = (const float*)d_in[0];
    const float* w1 = (const float*)d_in[1];
    const float* w2 = (const float*)d_in[2];
    const float* ff = (const float*)d_in[3];
    float* out = (float*)d_out;
    const int B = in_sizes[0] / 784;   // 4096

    float2* ws = (float2*)d_ws;
    precompute_trig<<<14, 256, 0, stream>>>(w1, w2, ff, ws);
    ringnn_kernel<<<B / 4, 256, 0, stream>>>(x, ws, out);   // 1024 = 4 blocks/CU
}